// Round 5
// baseline (446.597 us; speedup 1.0000x reference)
//
#include <hip/hip_runtime.h>
#include <hip/hip_bf16.h>

typedef short s16x8 __attribute__((ext_vector_type(8)));
typedef float f32x4 __attribute__((ext_vector_type(4)));
typedef float f32x2 __attribute__((ext_vector_type(2)));

#define TID threadIdx.x
#define N_IN 27

__device__ __forceinline__ float bf2f(unsigned short u) {
    unsigned v = ((unsigned)u) << 16;
    return __builtin_bit_cast(float, v);
}
__device__ __forceinline__ unsigned short f2bf(float f) {
    unsigned u = __builtin_bit_cast(unsigned, f);
    u += 0x7fffu + ((u >> 16) & 1u);
    return (unsigned short)(u >> 16);
}
__device__ __forceinline__ float lrelu_f(float x) { return fmaxf(x, 0.33f * x); }

// lrelu(pv+q.x), lrelu(pv+q.y) -> packed bf16x2 using HW v_cvt_pk_bf16_f32
__device__ __forceinline__ unsigned lrelu_pack(float pv, f32x2 q) {
    f32x2 s = q + pv;
    f32x2 m = s * 0.33f;
    f32x2 r = __builtin_elementwise_max(s, m);
    unsigned u;
    asm("v_cvt_pk_bf16_f32 %0, %1, %2" : "=v"(u) : "v"(r.x), "v"(r.y));
    return u;
}

union FragU { s16x8 v; uint4 q; unsigned w[4]; };

// ------------------------------------------------------------------
// Kernel 0: dtype detect. flag=1 -> bf16 inputs, 0 -> f32.
// ------------------------------------------------------------------
__global__ __launch_bounds__(256) void k_detect(const unsigned* __restrict__ w, int* __restrict__ flag) {
    __shared__ int cnt;
    if (TID == 0) cnt = 0;
    __syncthreads();
    int c = 0;
    for (int k = TID; k < 1024; k += 256) {
        unsigned e = (w[k] >> 23) & 0xFFu;
        c += (e >= 160u) ? 1 : 0;
    }
    atomicAdd(&cnt, c);
    __syncthreads();
    if (TID == 0) *flag = (cnt > 512) ? 1 : 0;
}

// ------------------------------------------------------------------
// Kernel 0b: mirror inputs to bf16. Big tensors skipped when already bf16.
// ------------------------------------------------------------------
struct ConvArgs {
    const void* src[N_IN];
    unsigned short* dst[N_IN];
    int n[N_IN];
};

__global__ __launch_bounds__(256) void k_convert(ConvArgs A, const int* __restrict__ flag) {
    const int t = blockIdx.y;
    const int n = A.n[t];
    const int fl = *flag;
    if (fl && n >= 1000000) return;   // big tensors read directly when bf16
    unsigned short* d = A.dst[t];
    const int npair = n >> 1;
    const int stride = gridDim.x * 256;
    if (fl) {
        const unsigned* s = (const unsigned*)A.src[t];
        for (int i = blockIdx.x * 256 + TID; i < npair; i += stride) ((unsigned*)d)[i] = s[i];
        if ((n & 1) && blockIdx.x == 0 && TID == 0) d[n - 1] = ((const unsigned short*)A.src[t])[n - 1];
    } else {
        const float* s = (const float*)A.src[t];
        for (int i = blockIdx.x * 256 + TID; i < npair; i += stride) {
            unsigned u;
            float a = s[2 * i], b = s[2 * i + 1];
            asm("v_cvt_pk_bf16_f32 %0, %1, %2" : "=v"(u) : "v"(a), "v"(b));
            ((unsigned*)d)[i] = u;
        }
        if ((n & 1) && blockIdx.x == 0 && TID == 0) d[n - 1] = f2bf(s[n - 1]);
    }
}

// ------------------------------------------------------------------
// Kernel 1: A1[b,c,i], B1[b,c,j] (biased). grid (256 r, 8 b, 2 v), block 128.
// ------------------------------------------------------------------
__global__ __launch_bounds__(128) void k_l1(
    const unsigned short* __restrict__ x,
    const unsigned short* __restrict__ w1a, const unsigned short* __restrict__ b1a,
    const unsigned short* __restrict__ w1b, const unsigned short* __restrict__ b1b,
    float* __restrict__ A1, float* __restrict__ B1)
{
    const int r = blockIdx.x, b = blockIdx.y, v = blockIdx.z;
    const int tid = TID;
    __shared__ float xr[256];
    const unsigned short* xb = x + b * 65536;
    if (v == 0) {
        xr[tid]       = bf2f(xb[r * 256 + tid]);
        xr[tid + 128] = bf2f(xb[r * 256 + tid + 128]);
    } else {
        xr[tid]       = bf2f(xb[tid * 256 + r]);
        xr[tid + 128] = bf2f(xb[(tid + 128) * 256 + r]);
    }
    __syncthreads();
    const unsigned short* w    = v ? w1b : w1a;
    const unsigned short* bias = v ? b1b : b1a;
    float* OUT = v ? B1 : A1;
    float acc = bf2f(bias[tid]);
    const unsigned short* wr = w + tid * 256;
    #pragma unroll 4
    for (int q = 0; q < 256; q += 8) {
        uint4 pk = *(const uint4*)(wr + q);
        unsigned ww0 = pk.x, ww1 = pk.y, ww2 = pk.z, ww3 = pk.w;
        acc += xr[q + 0] * bf2f((unsigned short)ww0) + xr[q + 1] * bf2f((unsigned short)(ww0 >> 16));
        acc += xr[q + 2] * bf2f((unsigned short)ww1) + xr[q + 3] * bf2f((unsigned short)(ww1 >> 16));
        acc += xr[q + 4] * bf2f((unsigned short)ww2) + xr[q + 5] * bf2f((unsigned short)(ww2 >> 16));
        acc += xr[q + 6] * bf2f((unsigned short)ww3) + xr[q + 7] * bf2f((unsigned short)(ww3 >> 16));
    }
    OUT[b * 32768 + tid * 256 + r] = acc;
}

// ------------------------------------------------------------------
// Kernel 2: partial[s,bw,p,r] = sum_{c in slice16, q} lrelu(P[c,r]+Q[c,q]) * W[p,c,q]
// grid (2 rt, 8 s, 16 bw), block 512 = 8 waves: 4 p-slices (p64) x 2 r-slices (r64).
// Q/P staged to LDS once; K-loop barrier-free.
// ------------------------------------------------------------------
__global__ __launch_bounds__(512) void k_e2e(
    const float* __restrict__ A1, const float* __restrict__ B1,
    const unsigned short* __restrict__ w2a_m, const unsigned short* __restrict__ w2b_m,
    const unsigned short* __restrict__ w2a_r, const unsigned short* __restrict__ w2b_r,
    const int* __restrict__ flag,
    float* __restrict__ part)
{
    const int rt = blockIdx.x;
    const int s  = blockIdx.y;
    const int bw = blockIdx.z;
    const int b = bw >> 1, which = bw & 1;
    const int fl = *flag;
    const float* P = (which ? B1 : A1) + b * 32768;
    const float* Q = (which ? A1 : B1) + b * 32768;
    const unsigned short* W = which ? (fl ? w2b_r : w2b_m) : (fl ? w2a_r : w2a_m);
    const int c0 = s * 16, r0 = rt * 128;

    __shared__ float Qs[16][256];
    __shared__ float Ps[16][128];

    const int tid = TID;
    {
        const float4* Qg = (const float4*)(Q + c0 * 256);
        float4* Qd = (float4*)&Qs[0][0];
        Qd[tid]       = Qg[tid];
        Qd[tid + 512] = Qg[tid + 512];
        int row = tid >> 5, col = tid & 31;
        *(float4*)&Ps[row][col * 4] = *(const float4*)&P[(c0 + row) * 256 + r0 + col * 4];
    }
    __syncthreads();

    const int wave = tid >> 6, lane = tid & 63, quad = lane >> 4, l16 = lane & 15;
    const int wi = wave & 3, wj = wave >> 2;       // p-slice, r-slice
    const int pbase = wi * 64;
    const int rbase = wj * 64;

    f32x4 acc[4][4] = {};

    // hoisted W row pointers (p rows this wave touches)
    const unsigned short* Wrow[4];
    #pragma unroll
    for (int pf = 0; pf < 4; ++pf)
        Wrow[pf] = W + (size_t)(pbase + pf * 16 + l16) * 32768 + c0 * 256;

    for (int c = 0; c < 16; ++c) {
        float pv[4];
        #pragma unroll
        for (int nf = 0; nf < 4; ++nf) pv[nf] = Ps[c][rbase + nf * 16 + l16];
        #pragma unroll
        for (int q0 = 0; q0 < 8; ++q0) {
            const f32x2* qp = (const f32x2*)&Qs[c][q0 * 32 + quad * 8];
            FragU af[4];
            #pragma unroll
            for (int pf = 0; pf < 4; ++pf)
                af[pf].q = *(const uint4*)(Wrow[pf] + c * 256 + q0 * 32 + quad * 8);
            #pragma unroll
            for (int nf = 0; nf < 4; ++nf) {
                FragU hb;
                hb.w[0] = lrelu_pack(pv[nf], qp[0]);
                hb.w[1] = lrelu_pack(pv[nf], qp[1]);
                hb.w[2] = lrelu_pack(pv[nf], qp[2]);
                hb.w[3] = lrelu_pack(pv[nf], qp[3]);
                #pragma unroll
                for (int pf = 0; pf < 4; ++pf)
                    acc[pf][nf] = __builtin_amdgcn_mfma_f32_16x16x32_bf16(af[pf].v, hb.v, acc[pf][nf], 0, 0, 0);
            }
        }
    }
    float* pb = part + (size_t)(s * 16 + bw) * 65536;
    #pragma unroll
    for (int pf = 0; pf < 4; ++pf)
        #pragma unroll
        for (int nf = 0; nf < 4; ++nf)
            #pragma unroll
            for (int t = 0; t < 4; ++t) {
                int p = pbase + pf * 16 + quad * 4 + t;
                int r = r0 + rbase + nf * 16 + l16;
                pb[p * 256 + r] = acc[pf][nf][t];
            }
}

// ------------------------------------------------------------------
// Kernel 2b: A2/B2 = sum_s partial + bias. grid (64, 16), block 256.
// ------------------------------------------------------------------
__global__ __launch_bounds__(256) void k_red(
    const float* __restrict__ part,
    const unsigned short* __restrict__ b2a, const unsigned short* __restrict__ b2b,
    float* __restrict__ A2, float* __restrict__ B2)
{
    const int bw = blockIdx.y; const int b = bw >> 1, which = bw & 1;
    const int idx = blockIdx.x * 256 + TID;   // float4 index 0..16383
    const float4* pp = (const float4*)part;
    float4 acc = make_float4(0.f, 0.f, 0.f, 0.f);
    #pragma unroll
    for (int s = 0; s < 8; ++s) {
        float4 v = pp[(size_t)(s * 16 + bw) * 16384 + idx];
        acc.x += v.x; acc.y += v.y; acc.z += v.z; acc.w += v.w;
    }
    const int p = idx >> 6;
    const float bias = bf2f((which ? b2b : b2a)[p]);
    acc.x += bias; acc.y += bias; acc.z += bias; acc.w += bias;
    float* OUT = (which ? B2 : A2) + b * 65536;
    ((float4*)OUT)[idx] = acc;
}

// ------------------------------------------------------------------
// Kernel 3: nodes_raw[b,i,p] += sum_{c in slice, q} lrelu(A2[c,i]+B2[c,q]) * e2n_w[p,c,q]
// grid (16 it, 8 b, 8 sn), block 256 (4 waves, c-split). Barrier-free; atomic out.
// ------------------------------------------------------------------
__global__ __launch_bounds__(256) void k_e2n(
    const float* __restrict__ A2, const float* __restrict__ B2,
    const unsigned short* __restrict__ e2nw,
    float* __restrict__ nodes_raw)
{
    const int it = blockIdx.x, b = blockIdx.y, sn = blockIdx.z;
    const int tid = TID, wave = tid >> 6, lane = tid & 63, quad = lane >> 4, l16 = lane & 15;
    const int i0 = it * 16;
    const int c0 = sn * 32 + wave * 8;
    const float* Ab = A2 + b * 65536;
    const float* Bb = B2 + b * 65536;
    f32x4 acc = {};
    for (int cc = 0; cc < 8; ++cc) {
        const int c = c0 + cc;
        const float pv = Ab[c * 256 + i0 + l16];
        const float* Brow = Bb + c * 256;
        const unsigned short* Wrow = e2nw + (size_t)l16 * 65536 + c * 256;
        #pragma unroll
        for (int q0 = 0; q0 < 8; ++q0) {
            const f32x2* qp = (const f32x2*)&Brow[q0 * 32 + quad * 8];
            FragU a;
            if (l16 < 8) a.q = *(const uint4*)(Wrow + q0 * 32 + quad * 8);
            else         a.q = make_uint4(0u, 0u, 0u, 0u);
            FragU hb;
            hb.w[0] = lrelu_pack(pv, qp[0]);
            hb.w[1] = lrelu_pack(pv, qp[1]);
            hb.w[2] = lrelu_pack(pv, qp[2]);
            hb.w[3] = lrelu_pack(pv, qp[3]);
            acc = __builtin_amdgcn_mfma_f32_16x16x32_bf16(a.v, hb.v, acc, 0, 0, 0);
        }
    }
    __shared__ float red[4][16][16];
    #pragma unroll
    for (int t = 0; t < 4; ++t) red[wave][quad * 4 + t][l16] = acc[t];
    __syncthreads();
    const int row = tid >> 4, col = tid & 15;
    if (row < 8) {
        float ssum = red[0][row][col] + red[1][row][col] + red[2][row][col] + red[3][row][col];
        atomicAdd(&nodes_raw[b * 2048 + (i0 + col) * 8 + row], ssum);
    }
}

// ------------------------------------------------------------------
// Kernel 3b: adjacency bitmasks via ballot. grid (8, 8 b), block 256.
// ------------------------------------------------------------------
__global__ __launch_bounds__(256) void k_adj(
    const unsigned short* __restrict__ xm,
    unsigned long long* __restrict__ adjw, float* __restrict__ rdegw)
{
    const int b = blockIdx.y;
    const int tid = TID, wave = tid >> 6, lane = tid & 63;
    const int rbase = blockIdx.x * 32 + wave * 8;
    for (int rr = 0; rr < 8; ++rr) {
        const int row = rbase + rr;
        int d = 0;
        unsigned long long w[4];
        #pragma unroll
        for (int k = 0; k < 4; ++k) {
            float v = bf2f(xm[b * 65536 + row * 256 + k * 64 + lane]);
            w[k] = __ballot(v > 0.0f);
            d += __popcll(w[k]);
        }
        if (lane == 0) {
            #pragma unroll
            for (int k = 0; k < 4; ++k) adjw[(b * 256 + row) * 4 + k] = w[k];
            rdegw[b * 256 + row] = d ? 1.0f / (float)d : 0.0f;
        }
    }
}

// ------------------------------------------------------------------
// Kernel 4: graph/pool/readout/MLP. One block per batch.
// ------------------------------------------------------------------
__global__ __launch_bounds__(256) void k_tail(
    const unsigned long long* __restrict__ adjw, const float* __restrict__ rdegw,
    const float* __restrict__ nodes_raw, const unsigned short* __restrict__ e2n_b,
    const unsigned short* __restrict__ a11_w, const unsigned short* __restrict__ a11_b,
    const unsigned short* __restrict__ a12_w, const unsigned short* __restrict__ a12_b,
    const unsigned short* __restrict__ g1_w,  const unsigned short* __restrict__ g1_b,
    const unsigned short* __restrict__ a21_w, const unsigned short* __restrict__ a21_b,
    const unsigned short* __restrict__ a22_w, const unsigned short* __restrict__ a22_b,
    const unsigned short* __restrict__ d1_w,  const unsigned short* __restrict__ d1_b,
    const unsigned short* __restrict__ d2_w,  const unsigned short* __restrict__ d2_b,
    const unsigned short* __restrict__ d3_w,  const unsigned short* __restrict__ d3_b,
    const int* __restrict__ flag,
    void* __restrict__ outv)
{
    const int b = blockIdx.x;
    const int tid = TID;

    __shared__ unsigned long long adj[256][4];
    __shared__ float nod[256][8];
    __shared__ float rdeg[256];
    __shared__ float md[256];
    __shared__ float w1s[256];
    __shared__ float w2s[256];
    __shared__ int   selflag[256];
    __shared__ int   selidx[128];
    __shared__ float s1v[128];
    __shared__ float out1[128][8];
    __shared__ float aggL[128][8];
    __shared__ float h2L[128][8];
    __shared__ unsigned long long adj1[128][2];
    __shared__ float rdeg1[128];
    __shared__ float tA[128];
    __shared__ float w1t[128];
    __shared__ float w2t[128];
    __shared__ int   sel2flag[128];
    __shared__ int   sel2idx[64];
    __shared__ float s2v[64];
    __shared__ float out2[64][8];
    __shared__ float r1[16], r2[16], zz[16];
    __shared__ float z1[128];
    __shared__ float z2[64];

    if (tid < 128) { selidx[tid] = 0; s1v[tid] = 0.0f; }
    if (tid < 64)  { sel2idx[tid] = 0; s2v[tid] = 0.0f; }

    {
        #pragma unroll
        for (int k = 0; k < 4; ++k) adj[tid][k] = adjw[(b * 256 + tid) * 4 + k];
        rdeg[tid] = rdegw[b * 256 + tid];
        for (int f = 0; f < 8; ++f)
            nod[tid][f] = lrelu_f(nodes_raw[b * 2048 + tid * 8 + f] + bf2f(e2n_b[f]));
    }
    __syncthreads();
    {
        float s = 0.0f;
        for (int f = 0; f < 8; ++f) s += nod[tid][f] * bf2f(a11_w[f]);
        md[tid] = s * rdeg[tid];
    }
    __syncthreads();
    {
        float s = 0.0f;
        for (int k = 0; k < 4; ++k) {
            unsigned long long m = adj[tid][k];
            while (m) { int j = __builtin_ctzll(m); m &= m - 1; s += md[k * 64 + j]; }
        }
        w1s[tid] = lrelu_f(s + bf2f(a11_b[0]));
    }
    __syncthreads();
    md[tid] = w1s[tid] * bf2f(a12_w[0]) * rdeg[tid];
    __syncthreads();
    {
        float s = 0.0f;
        for (int k = 0; k < 4; ++k) {
            unsigned long long m = adj[tid][k];
            while (m) { int j = __builtin_ctzll(m); m &= m - 1; s += md[k * 64 + j]; }
        }
        w2s[tid] = 1.0f / (1.0f + expf(-(s + bf2f(a12_b[0]))));
    }
    __syncthreads();
    {
        const float my = w2s[tid];
        int cnt = 0;
        for (int j = 0; j < 256; ++j) {
            float o = w2s[j];
            cnt += (o > my) || (o == my && j < tid);
        }
        selflag[tid] = (cnt < 128) ? 1 : 0;
    }
    __syncthreads();
    if (selflag[tid]) {
        int pos = 0;
        for (int j = 0; j < tid; ++j) pos += selflag[j];
        if (pos < 128) { selidx[pos] = tid; s1v[pos] = w2s[tid]; }
    }
    __syncthreads();
    for (int k = tid; k < 1024; k += 256) {
        int t = k >> 3, f = k & 7;
        out1[t][f] = nod[selidx[t]][f] * (1.0f + s1v[t]);
    }
    __syncthreads();
    if (tid < 16) {
        int f = tid & 7;
        if (tid < 8) {
            float mx = -INFINITY;
            for (int t = 0; t < 128; ++t) mx = fmaxf(mx, out1[t][f]);
            r1[tid] = mx;
        } else {
            float s = 0.0f;
            for (int t = 0; t < 128; ++t) s += out1[t][f];
            r1[tid] = s * (1.0f / 128.0f);
        }
    }
    if (tid < 128) {
        unsigned long long wds[2] = {0ull, 0ull};
        const int gi = selidx[tid];
        for (int u = 0; u < 128; ++u) {
            const int gj = selidx[u];
            unsigned long long bit = (adj[gi][gj >> 6] >> (gj & 63)) & 1ull;
            wds[u >> 6] |= bit << (u & 63);
        }
        adj1[tid][0] = wds[0]; adj1[tid][1] = wds[1];
        int d = __popcll(wds[0]) + __popcll(wds[1]);
        rdeg1[tid] = d ? 1.0f / (float)d : 0.0f;
    }
    __syncthreads();
    {
        const int t = tid >> 1, f0 = (tid & 1) * 4;
        float a0 = 0, a1 = 0, a2 = 0, a3 = 0;
        for (int k = 0; k < 2; ++k) {
            unsigned long long m = adj1[t][k];
            while (m) {
                int u = __builtin_ctzll(m); m &= m - 1;
                int uu = k * 64 + u;
                float rr = rdeg1[uu];
                a0 += out1[uu][f0 + 0] * rr;
                a1 += out1[uu][f0 + 1] * rr;
                a2 += out1[uu][f0 + 2] * rr;
                a3 += out1[uu][f0 + 3] * rr;
            }
        }
        aggL[t][f0 + 0] = a0; aggL[t][f0 + 1] = a1; aggL[t][f0 + 2] = a2; aggL[t][f0 + 3] = a3;
    }
    __syncthreads();
    for (int k = tid; k < 1024; k += 256) {
        int t = k >> 3, fo = k & 7;
        float s = bf2f(g1_b[fo]);
        for (int f = 0; f < 8; ++f) s += aggL[t][f] * bf2f(g1_w[fo * 8 + f]);
        h2L[t][fo] = s;
    }
    __syncthreads();
    if (tid < 128) {
        float s = 0.0f;
        for (int f = 0; f < 8; ++f) s += h2L[tid][f] * bf2f(a21_w[f]);
        tA[tid] = s * rdeg1[tid];
    }
    __syncthreads();
    if (tid < 128) {
        float s = 0.0f;
        for (int k = 0; k < 2; ++k) {
            unsigned long long m = adj1[tid][k];
            while (m) { int u = __builtin_ctzll(m); m &= m - 1; s += tA[k * 64 + u]; }
        }
        w1t[tid] = lrelu_f(s + bf2f(a21_b[0]));
    }
    __syncthreads();
    if (tid < 128) tA[tid] = w1t[tid] * bf2f(a22_w[0]) * rdeg1[tid];
    __syncthreads();
    if (tid < 128) {
        float s = 0.0f;
        for (int k = 0; k < 2; ++k) {
            unsigned long long m = adj1[tid][k];
            while (m) { int u = __builtin_ctzll(m); m &= m - 1; s += tA[k * 64 + u]; }
        }
        w2t[tid] = 1.0f / (1.0f + expf(-(s + bf2f(a22_b[0]))));
    }
    __syncthreads();
    if (tid < 128) {
        const float my = w2t[tid];
        int cnt = 0;
        for (int u = 0; u < 128; ++u) {
            float o = w2t[u];
            cnt += (o > my) || (o == my && u < tid);
        }
        sel2flag[tid] = (cnt < 64) ? 1 : 0;
    }
    __syncthreads();
    if (tid < 128 && sel2flag[tid]) {
        int pos = 0;
        for (int u = 0; u < tid; ++u) pos += sel2flag[u];
        if (pos < 64) { sel2idx[pos] = tid; s2v[pos] = w2t[tid]; }
    }
    __syncthreads();
    for (int k = tid; k < 512; k += 256) {
        int u = k >> 3, f = k & 7;
        out2[u][f] = h2L[sel2idx[u]][f] * (1.0f + s2v[u]);
    }
    __syncthreads();
    if (tid < 16) {
        int f = tid & 7;
        if (tid < 8) {
            float mx = -INFINITY;
            for (int t = 0; t < 64; ++t) mx = fmaxf(mx, out2[t][f]);
            r2[tid] = mx;
        } else {
            float s = 0.0f;
            for (int t = 0; t < 64; ++t) s += out2[t][f];
            r2[tid] = s * (1.0f / 64.0f);
        }
    }
    __syncthreads();
    if (tid < 16) zz[tid] = r1[tid] + r2[tid];
    __syncthreads();
    if (tid < 128) {
        float s = bf2f(d1_b[tid]);
        for (int k = 0; k < 16; ++k) s += zz[k] * bf2f(d1_w[tid * 16 + k]);
        z1[tid] = lrelu_f(s);
    }
    __syncthreads();
    if (tid < 64) {
        float s = bf2f(d2_b[tid]);
        for (int k = 0; k < 128; ++k) s += z1[k] * bf2f(d2_w[tid * 128 + k]);
        z2[tid] = lrelu_f(s);
    }
    __syncthreads();
    if (tid == 0) {
        float s = bf2f(d3_b[0]);
        for (int k = 0; k < 64; ++k) s += z2[k] * bf2f(d3_w[k]);
        if (*flag) ((unsigned short*)outv)[b] = f2bf(s);
        else       ((float*)outv)[b] = s;
    }
}

// ------------------------------------------------------------------
extern "C" void kernel_launch(void* const* d_in, const int* in_sizes, int n_in,
                              void* d_out, int out_size, void* d_ws, size_t ws_size,
                              hipStream_t stream) {
    float* ws        = (float*)d_ws;
    float* A1        = ws;                     // 262144
    float* B1        = ws + 262144;            // 262144
    float* A2        = ws + 524288;            // 524288
    float* B2        = ws + 1048576;           // 524288
    float* nodes_raw = ws + 1572864;           // 16384
    float* rdegw     = ws + 1589248;           // 8192
    int*   flag      = (int*)(ws + 1597440);   // 4
    unsigned long long* adjw = (unsigned long long*)(ws + 1597444); // 8192 ull
    float* part      = ws + 1613832;           // 8388608
    unsigned short* mbase = (unsigned short*)(ws + 10002440);

    unsigned short* mir[N_IN];
    ConvArgs CA;
    {
        size_t off = 0;
        for (int i = 0; i < N_IN; ++i) {
            off = (off + 7) & ~(size_t)7;
            mir[i] = mbase + off;
            off += (size_t)in_sizes[i];
            CA.src[i] = d_in[i];
            CA.dst[i] = mir[i];
            CA.n[i]   = in_sizes[i];
        }
    }

    k_detect<<<dim3(1), 256, 0, stream>>>((const unsigned*)d_in[5], flag);
    k_convert<<<dim3(256, N_IN), 256, 0, stream>>>(CA, flag);
    hipMemsetAsync(nodes_raw, 0, 16384 * sizeof(float), stream);
    k_l1<<<dim3(256, 8, 2), 128, 0, stream>>>(mir[0], mir[1], mir[2], mir[3], mir[4], A1, B1);
    k_adj<<<dim3(8, 8), 256, 0, stream>>>(mir[0], adjw, rdegw);
    k_e2e<<<dim3(2, 8, 16), 512, 0, stream>>>(A1, B1,
        mir[5], mir[7],
        (const unsigned short*)d_in[5], (const unsigned short*)d_in[7],
        flag, part);
    k_red<<<dim3(64, 16), 256, 0, stream>>>(part, mir[6], mir[8], A2, B2);
    k_e2n<<<dim3(16, 8, 8), 256, 0, stream>>>(A2, B2, mir[9], nodes_raw);
    k_tail<<<dim3(8), 256, 0, stream>>>(adjw, rdegw, nodes_raw, mir[10],
        mir[11], mir[12], mir[13], mir[14], mir[15], mir[16], mir[17], mir[18],
        mir[19], mir[20], mir[21], mir[22], mir[23], mir[24], mir[25], mir[26],
        flag, d_out);
}

// Round 6
// 438.617 us; speedup vs baseline: 1.0182x; 1.0182x over previous
//
#include <hip/hip_runtime.h>

typedef short s16x8 __attribute__((ext_vector_type(8)));
typedef float f32x4 __attribute__((ext_vector_type(4)));
typedef float f32x2 __attribute__((ext_vector_type(2)));

#define TID threadIdx.x

__device__ __forceinline__ float lrelu_f(float x) { return fmaxf(x, 0.33f * x); }

// lrelu(pv+q.x), lrelu(pv+q.y) -> packed bf16x2 using HW v_cvt_pk_bf16_f32
__device__ __forceinline__ unsigned lrelu_pack(float pv, f32x2 q) {
    f32x2 s = q + pv;
    f32x2 m = s * 0.33f;
    f32x2 r = __builtin_elementwise_max(s, m);
    unsigned u;
    asm("v_cvt_pk_bf16_f32 %0, %1, %2" : "=v"(u) : "v"(r.x), "v"(r.y));
    return u;
}
__device__ __forceinline__ unsigned pk_bf16(float a, float b) {
    unsigned u;
    asm("v_cvt_pk_bf16_f32 %0, %1, %2" : "=v"(u) : "v"(a), "v"(b));
    return u;
}

union FragU { s16x8 v; uint4 q; unsigned w[4]; };

// ------------------------------------------------------------------
// Kernel 0: f32 -> bf16 mirrors for w2a, w2b, e2n_w. grid (512, 3).
// ------------------------------------------------------------------
__global__ __launch_bounds__(256) void k_convert(
    const float* __restrict__ sa, unsigned short* __restrict__ da, int na4,
    const float* __restrict__ sb, unsigned short* __restrict__ db, int nb4,
    const float* __restrict__ sc, unsigned short* __restrict__ dc, int nc4)
{
    const float* s; unsigned short* d; int n4;
    if (blockIdx.y == 0)      { s = sa; d = da; n4 = na4; }
    else if (blockIdx.y == 1) { s = sb; d = db; n4 = nb4; }
    else                      { s = sc; d = dc; n4 = nc4; }
    const int stride = gridDim.x * 256;
    for (int i = blockIdx.x * 256 + TID; i < n4; i += stride) {
        float4 v = ((const float4*)s)[i];
        ((uint2*)d)[i] = make_uint2(pk_bf16(v.x, v.y), pk_bf16(v.z, v.w));
    }
}

// ------------------------------------------------------------------
// Kernel 1: A1[b,c,i] = sum_j x[b,i,j]*w1a[c,j]+b1a[c] (v=0)
//           B1[b,c,j] = sum_i x[b,i,j]*w1b[c,i]+b1b[c] (v=1)   all f32.
// grid (256 r, 8 b, 2 v), block 128 (c)
// ------------------------------------------------------------------
__global__ __launch_bounds__(128) void k_l1(
    const float* __restrict__ x,
    const float* __restrict__ w1a, const float* __restrict__ b1a,
    const float* __restrict__ w1b, const float* __restrict__ b1b,
    float* __restrict__ A1, float* __restrict__ B1)
{
    const int r = blockIdx.x, b = blockIdx.y, v = blockIdx.z;
    const int tid = TID;
    __shared__ float xr[256];
    const float* xb = x + b * 65536;
    if (v == 0) {
        xr[tid]       = xb[r * 256 + tid];
        xr[tid + 128] = xb[r * 256 + tid + 128];
    } else {
        xr[tid]       = xb[tid * 256 + r];
        xr[tid + 128] = xb[(tid + 128) * 256 + r];
    }
    __syncthreads();
    const float* w    = v ? w1b : w1a;
    const float* bias = v ? b1b : b1a;
    float* OUT = v ? B1 : A1;
    float acc = bias[tid];
    const float* wr = w + tid * 256;
    #pragma unroll 4
    for (int q = 0; q < 256; q += 8) {
        float4 a = *(const float4*)(wr + q);
        float4 c = *(const float4*)(wr + q + 4);
        acc += xr[q + 0] * a.x + xr[q + 1] * a.y + xr[q + 2] * a.z + xr[q + 3] * a.w;
        acc += xr[q + 4] * c.x + xr[q + 5] * c.y + xr[q + 6] * c.z + xr[q + 7] * c.w;
    }
    OUT[b * 32768 + tid * 256 + r] = acc;
}

// ------------------------------------------------------------------
// Kernel 2: partial[s,bw,p,r] = sum_{c in slice16, q} lrelu(P[c,r]+Q[c,q]) * W[p,c,q]
// grid (2 rt, 8 s, 16 bw), block 512 = 8 waves: 4 p-slices x 2 r-slices.
// Software-pipelined: W frags + Q LDS + P row prefetched one step ahead.
// ------------------------------------------------------------------
__global__ __launch_bounds__(512) void k_e2e(
    const float* __restrict__ A1, const float* __restrict__ B1,
    const unsigned short* __restrict__ w2aM, const unsigned short* __restrict__ w2bM,
    float* __restrict__ part)
{
    const int rt = blockIdx.x;
    const int s  = blockIdx.y;
    const int bw = blockIdx.z;
    const int b = bw >> 1, which = bw & 1;
    const float* P = (which ? B1 : A1) + b * 32768;
    const float* Q = (which ? A1 : B1) + b * 32768;
    const unsigned short* W = which ? w2bM : w2aM;
    const int c0 = s * 16, r0 = rt * 128;

    __shared__ float Qs[16][256];
    __shared__ float Ps[16][128];

    const int tid = TID;
    {
        const float4* Qg = (const float4*)(Q + c0 * 256);
        float4* Qd = (float4*)&Qs[0][0];
        Qd[tid]       = Qg[tid];
        Qd[tid + 512] = Qg[tid + 512];
        int row = tid >> 5, col = tid & 31;
        *(float4*)&Ps[row][col * 4] = *(const float4*)&P[(c0 + row) * 256 + r0 + col * 4];
    }
    __syncthreads();

    const int wave = tid >> 6, lane = tid & 63, quad = lane >> 4, l16 = lane & 15;
    const int wi = wave & 3, wj = wave >> 2;
    const int pbase = wi * 64, rbase = wj * 64;

    f32x4 acc[4][4] = {};

    const unsigned short* Wrow[4];
    #pragma unroll
    for (int pf = 0; pf < 4; ++pf)
        Wrow[pf] = W + (size_t)(pbase + pf * 16 + l16) * 32768 + c0 * 256 + quad * 8;

    FragU af[2][4];
    f32x2 qp[2][4];
    float pv[4], pvn[4];

    // preload step (c=0, q0=0)
    #pragma unroll
    for (int pf = 0; pf < 4; ++pf) af[0][pf].q = *(const uint4*)(Wrow[pf]);
    #pragma unroll
    for (int k = 0; k < 4; ++k) qp[0][k] = *(const f32x2*)&Qs[0][quad * 8 + 2 * k];
    #pragma unroll
    for (int nf = 0; nf < 4; ++nf) pv[nf] = Ps[0][rbase + nf * 16 + l16];

    for (int c = 0; c < 16; ++c) {
        #pragma unroll
        for (int q0 = 0; q0 < 8; ++q0) {
            const int cur = q0 & 1, nxt = cur ^ 1;
            const int cn = (q0 == 7) ? c + 1 : c;
            const int qn = (q0 + 1) & 7;
            if (cn < 16) {
                #pragma unroll
                for (int pf = 0; pf < 4; ++pf)
                    af[nxt][pf].q = *(const uint4*)(Wrow[pf] + cn * 256 + qn * 32);
                #pragma unroll
                for (int k = 0; k < 4; ++k)
                    qp[nxt][k] = *(const f32x2*)&Qs[cn][qn * 32 + quad * 8 + 2 * k];
            }
            if (q0 == 4 && c + 1 < 16) {
                #pragma unroll
                for (int nf = 0; nf < 4; ++nf) pvn[nf] = Ps[c + 1][rbase + nf * 16 + l16];
            }
            #pragma unroll
            for (int nf = 0; nf < 4; ++nf) {
                FragU hb;
                hb.w[0] = lrelu_pack(pv[nf], qp[cur][0]);
                hb.w[1] = lrelu_pack(pv[nf], qp[cur][1]);
                hb.w[2] = lrelu_pack(pv[nf], qp[cur][2]);
                hb.w[3] = lrelu_pack(pv[nf], qp[cur][3]);
                #pragma unroll
                for (int pf = 0; pf < 4; ++pf)
                    acc[pf][nf] = __builtin_amdgcn_mfma_f32_16x16x32_bf16(af[cur][pf].v, hb.v, acc[pf][nf], 0, 0, 0);
            }
            if (q0 == 7) {
                #pragma unroll
                for (int nf = 0; nf < 4; ++nf) pv[nf] = pvn[nf];
            }
        }
    }
    float* pb = part + (size_t)(s * 16 + bw) * 65536;
    #pragma unroll
    for (int pf = 0; pf < 4; ++pf)
        #pragma unroll
        for (int nf = 0; nf < 4; ++nf)
            #pragma unroll
            for (int t = 0; t < 4; ++t) {
                int p = pbase + pf * 16 + quad * 4 + t;
                int r = r0 + rbase + nf * 16 + l16;
                pb[p * 256 + r] = acc[pf][nf][t];
            }
}

// ------------------------------------------------------------------
// Kernel 2b: A2/B2 = sum_s partial + bias. grid (64, 16), block 256.
// ------------------------------------------------------------------
__global__ __launch_bounds__(256) void k_red(
    const float* __restrict__ part,
    const float* __restrict__ b2a, const float* __restrict__ b2b,
    float* __restrict__ A2, float* __restrict__ B2)
{
    const int bw = blockIdx.y; const int b = bw >> 1, which = bw & 1;
    const int idx = blockIdx.x * 256 + TID;
    const float4* pp = (const float4*)part;
    float4 acc = make_float4(0.f, 0.f, 0.f, 0.f);
    #pragma unroll
    for (int s = 0; s < 8; ++s) {
        float4 v = pp[(size_t)(s * 16 + bw) * 16384 + idx];
        acc.x += v.x; acc.y += v.y; acc.z += v.z; acc.w += v.w;
    }
    const int p = idx >> 6;
    const float bias = (which ? b2b : b2a)[p];
    acc.x += bias; acc.y += bias; acc.z += bias; acc.w += bias;
    float* OUT = (which ? B2 : A2) + b * 65536;
    ((float4*)OUT)[idx] = acc;
}

// ------------------------------------------------------------------
// Kernel 3: nodes_raw[b,i,p] += sum_{c slice,q} lrelu(A2[c,i]+B2[c,q])*e2n_w[p,c,q]
// grid (16 it, 8 b, 8 sn), block 256 (4 waves c-split), prefetched, atomic out.
// ------------------------------------------------------------------
__global__ __launch_bounds__(256) void k_e2n(
    const float* __restrict__ A2, const float* __restrict__ B2,
    const unsigned short* __restrict__ e2nw,
    float* __restrict__ nodes_raw)
{
    const int it = blockIdx.x, b = blockIdx.y, sn = blockIdx.z;
    const int tid = TID, wave = tid >> 6, lane = tid & 63, quad = lane >> 4, l16 = lane & 15;
    const int i0 = it * 16;
    const int c0 = sn * 32 + wave * 8;
    const float* Ab = A2 + b * 65536;
    const float* Bb = B2 + b * 65536;
    const float* Brow0 = Bb + c0 * 256 + quad * 8;
    const unsigned short* Wrow0 = e2nw + (size_t)l16 * 65536 + c0 * 256 + quad * 8;

    f32x4 acc = {};
    FragU af[2];
    f32x2 qp[2][4];
    float pv, pvn;

    if (l16 < 8) af[0].q = *(const uint4*)(Wrow0);
    else         af[0].q = make_uint4(0u, 0u, 0u, 0u);
    #pragma unroll
    for (int k = 0; k < 4; ++k) qp[0][k] = *(const f32x2*)(Brow0 + 2 * k);
    pv = Ab[c0 * 256 + i0 + l16];

    for (int cc = 0; cc < 8; ++cc) {
        #pragma unroll
        for (int q0 = 0; q0 < 8; ++q0) {
            const int cur = q0 & 1, nxt = cur ^ 1;
            const int cn = (q0 == 7) ? cc + 1 : cc;
            const int qn = (q0 + 1) & 7;
            if (cn < 8) {
                if (l16 < 8) af[nxt].q = *(const uint4*)(Wrow0 + cn * 256 + qn * 32);
                else         af[nxt].q = make_uint4(0u, 0u, 0u, 0u);
                #pragma unroll
                for (int k = 0; k < 4; ++k)
                    qp[nxt][k] = *(const f32x2*)(Brow0 + cn * 256 + qn * 32 + 2 * k);
            }
            if (q0 == 4 && cc + 1 < 8) pvn = Ab[(c0 + cc + 1) * 256 + i0 + l16];
            FragU hb;
            hb.w[0] = lrelu_pack(pv, qp[cur][0]);
            hb.w[1] = lrelu_pack(pv, qp[cur][1]);
            hb.w[2] = lrelu_pack(pv, qp[cur][2]);
            hb.w[3] = lrelu_pack(pv, qp[cur][3]);
            acc = __builtin_amdgcn_mfma_f32_16x16x32_bf16(af[cur].v, hb.v, acc, 0, 0, 0);
            if (q0 == 7) pv = pvn;
        }
    }
    __shared__ float red[4][16][16];
    #pragma unroll
    for (int t = 0; t < 4; ++t) red[wave][quad * 4 + t][l16] = acc[t];
    __syncthreads();
    const int row = tid >> 4, col = tid & 15;
    if (row < 8) {
        float ssum = red[0][row][col] + red[1][row][col] + red[2][row][col] + red[3][row][col];
        atomicAdd(&nodes_raw[b * 2048 + (i0 + col) * 8 + row], ssum);
    }
}

// ------------------------------------------------------------------
// Kernel 3b: adjacency bitmasks via ballot. grid (8, 8 b), block 256.
// ------------------------------------------------------------------
__global__ __launch_bounds__(256) void k_adj(
    const float* __restrict__ x,
    unsigned long long* __restrict__ adjw, float* __restrict__ rdegw)
{
    const int b = blockIdx.y;
    const int tid = TID, wave = tid >> 6, lane = tid & 63;
    const int rbase = blockIdx.x * 32 + wave * 8;
    for (int rr = 0; rr < 8; ++rr) {
        const int row = rbase + rr;
        int d = 0;
        unsigned long long w[4];
        #pragma unroll
        for (int k = 0; k < 4; ++k) {
            float v = x[b * 65536 + row * 256 + k * 64 + lane];
            w[k] = __ballot(v > 0.0f);
            d += __popcll(w[k]);
        }
        if (lane == 0) {
            #pragma unroll
            for (int k = 0; k < 4; ++k) adjw[(b * 256 + row) * 4 + k] = w[k];
            rdegw[b * 256 + row] = d ? 1.0f / (float)d : 0.0f;
        }
    }
}

// ------------------------------------------------------------------
// Kernel 4: graph/pool/readout/MLP. One block per batch. f32 weights/out.
// ------------------------------------------------------------------
__global__ __launch_bounds__(256) void k_tail(
    const unsigned long long* __restrict__ adjw, const float* __restrict__ rdegw,
    const float* __restrict__ nodes_raw, const float* __restrict__ e2n_b,
    const float* __restrict__ a11_w, const float* __restrict__ a11_b,
    const float* __restrict__ a12_w, const float* __restrict__ a12_b,
    const float* __restrict__ g1_w,  const float* __restrict__ g1_b,
    const float* __restrict__ a21_w, const float* __restrict__ a21_b,
    const float* __restrict__ a22_w, const float* __restrict__ a22_b,
    const float* __restrict__ d1_w,  const float* __restrict__ d1_b,
    const float* __restrict__ d2_w,  const float* __restrict__ d2_b,
    const float* __restrict__ d3_w,  const float* __restrict__ d3_b,
    float* __restrict__ out)
{
    const int b = blockIdx.x;
    const int tid = TID;

    __shared__ unsigned long long adj[256][4];
    __shared__ float nod[256][8];
    __shared__ float rdeg[256];
    __shared__ float md[256];
    __shared__ float w1s[256];
    __shared__ float w2s[256];
    __shared__ int   selflag[256];
    __shared__ int   selidx[128];
    __shared__ float s1v[128];
    __shared__ float out1[128][8];
    __shared__ float aggL[128][8];
    __shared__ float h2L[128][8];
    __shared__ unsigned long long adj1[128][2];
    __shared__ float rdeg1[128];
    __shared__ float tA[128];
    __shared__ float w1t[128];
    __shared__ float w2t[128];
    __shared__ int   sel2flag[128];
    __shared__ int   sel2idx[64];
    __shared__ float s2v[64];
    __shared__ float out2[64][8];
    __shared__ float r1[16], r2[16], zz[16];
    __shared__ float z1[128];
    __shared__ float z2[64];

    if (tid < 128) { selidx[tid] = 0; s1v[tid] = 0.0f; }
    if (tid < 64)  { sel2idx[tid] = 0; s2v[tid] = 0.0f; }

    {
        #pragma unroll
        for (int k = 0; k < 4; ++k) adj[tid][k] = adjw[(b * 256 + tid) * 4 + k];
        rdeg[tid] = rdegw[b * 256 + tid];
        for (int f = 0; f < 8; ++f)
            nod[tid][f] = lrelu_f(nodes_raw[b * 2048 + tid * 8 + f] + e2n_b[f]);
    }
    __syncthreads();
    {
        float s = 0.0f;
        for (int f = 0; f < 8; ++f) s += nod[tid][f] * a11_w[f];
        md[tid] = s * rdeg[tid];
    }
    __syncthreads();
    {
        float s = 0.0f;
        for (int k = 0; k < 4; ++k) {
            unsigned long long m = adj[tid][k];
            while (m) { int j = __builtin_ctzll(m); m &= m - 1; s += md[k * 64 + j]; }
        }
        w1s[tid] = lrelu_f(s + a11_b[0]);
    }
    __syncthreads();
    md[tid] = w1s[tid] * a12_w[0] * rdeg[tid];
    __syncthreads();
    {
        float s = 0.0f;
        for (int k = 0; k < 4; ++k) {
            unsigned long long m = adj[tid][k];
            while (m) { int j = __builtin_ctzll(m); m &= m - 1; s += md[k * 64 + j]; }
        }
        w2s[tid] = 1.0f / (1.0f + expf(-(s + a12_b[0])));
    }
    __syncthreads();
    {
        const float my = w2s[tid];
        int cnt = 0;
        for (int j = 0; j < 256; ++j) {
            float o = w2s[j];
            cnt += (o > my) || (o == my && j < tid);
        }
        selflag[tid] = (cnt < 128) ? 1 : 0;
    }
    __syncthreads();
    if (selflag[tid]) {
        int pos = 0;
        for (int j = 0; j < tid; ++j) pos += selflag[j];
        if (pos < 128) { selidx[pos] = tid; s1v[pos] = w2s[tid]; }
    }
    __syncthreads();
    for (int k = tid; k < 1024; k += 256) {
        int t = k >> 3, f = k & 7;
        out1[t][f] = nod[selidx[t]][f] * (1.0f + s1v[t]);
    }
    __syncthreads();
    if (tid < 16) {
        int f = tid & 7;
        if (tid < 8) {
            float mx = -INFINITY;
            for (int t = 0; t < 128; ++t) mx = fmaxf(mx, out1[t][f]);
            r1[tid] = mx;
        } else {
            float s = 0.0f;
            for (int t = 0; t < 128; ++t) s += out1[t][f];
            r1[tid] = s * (1.0f / 128.0f);
        }
    }
    if (tid < 128) {
        unsigned long long wds[2] = {0ull, 0ull};
        const int gi = selidx[tid];
        for (int u = 0; u < 128; ++u) {
            const int gj = selidx[u];
            unsigned long long bit = (adj[gi][gj >> 6] >> (gj & 63)) & 1ull;
            wds[u >> 6] |= bit << (u & 63);
        }
        adj1[tid][0] = wds[0]; adj1[tid][1] = wds[1];
        int d = __popcll(wds[0]) + __popcll(wds[1]);
        rdeg1[tid] = d ? 1.0f / (float)d : 0.0f;
    }
    __syncthreads();
    {
        const int t = tid >> 1, f0 = (tid & 1) * 4;
        float a0 = 0, a1 = 0, a2 = 0, a3 = 0;
        for (int k = 0; k < 2; ++k) {
            unsigned long long m = adj1[t][k];
            while (m) {
                int u = __builtin_ctzll(m); m &= m - 1;
                int uu = k * 64 + u;
                float rr = rdeg1[uu];
                a0 += out1[uu][f0 + 0] * rr;
                a1 += out1[uu][f0 + 1] * rr;
                a2 += out1[uu][f0 + 2] * rr;
                a3 += out1[uu][f0 + 3] * rr;
            }
        }
        aggL[t][f0 + 0] = a0; aggL[t][f0 + 1] = a1; aggL[t][f0 + 2] = a2; aggL[t][f0 + 3] = a3;
    }
    __syncthreads();
    for (int k = tid; k < 1024; k += 256) {
        int t = k >> 3, fo = k & 7;
        float s = g1_b[fo];
        for (int f = 0; f < 8; ++f) s += aggL[t][f] * g1_w[fo * 8 + f];
        h2L[t][fo] = s;
    }
    __syncthreads();
    if (tid < 128) {
        float s = 0.0f;
        for (int f = 0; f < 8; ++f) s += h2L[tid][f] * a21_w[f];
        tA[tid] = s * rdeg1[tid];
    }
    __syncthreads();
    if (tid < 128) {
        float s = 0.0f;
        for (int k = 0; k < 2; ++k) {
            unsigned long long m = adj1[tid][k];
            while (m) { int u = __builtin_ctzll(m); m &= m - 1; s += tA[k * 64 + u]; }
        }
        w1t[tid] = lrelu_f(s + a21_b[0]);
    }
    __syncthreads();
    if (tid < 128) tA[tid] = w1t[tid] * a22_w[0] * rdeg1[tid];
    __syncthreads();
    if (tid < 128) {
        float s = 0.0f;
        for (int k = 0; k < 2; ++k) {
            unsigned long long m = adj1[tid][k];
            while (m) { int u = __builtin_ctzll(m); m &= m - 1; s += tA[k * 64 + u]; }
        }
        w2t[tid] = 1.0f / (1.0f + expf(-(s + a22_b[0])));
    }
    __syncthreads();
    if (tid < 128) {
        const float my = w2t[tid];
        int cnt = 0;
        for (int u = 0; u < 128; ++u) {
            float o = w2t[u];
            cnt += (o > my) || (o == my && u < tid);
        }
        sel2flag[tid] = (cnt < 64) ? 1 : 0;
    }
    __syncthreads();
    if (tid < 128 && sel2flag[tid]) {
        int pos = 0;
        for (int u = 0; u < tid; ++u) pos += sel2flag[u];
        if (pos < 64) { sel2idx[pos] = tid; s2v[pos] = w2t[tid]; }
    }
    __syncthreads();
    for (int k = tid; k < 512; k += 256) {
        int u = k >> 3, f = k & 7;
        out2[u][f] = h2L[sel2idx[u]][f] * (1.0f + s2v[u]);
    }
    __syncthreads();
    if (tid < 16) {
        int f = tid & 7;
        if (tid < 8) {
            float mx = -INFINITY;
            for (int t = 0; t < 64; ++t) mx = fmaxf(mx, out2[t][f]);
            r2[tid] = mx;
        } else {
            float s = 0.0f;
            for (int t = 0; t < 64; ++t) s += out2[t][f];
            r2[tid] = s * (1.0f / 64.0f);
        }
    }
    __syncthreads();
    if (tid < 16) zz[tid] = r1[tid] + r2[tid];
    __syncthreads();
    if (tid < 128) {
        float s = d1_b[tid];
        for (int k = 0; k < 16; ++k) s += zz[k] * d1_w[tid * 16 + k];
        z1[tid] = lrelu_f(s);
    }
    __syncthreads();
    if (tid < 64) {
        float s = d2_b[tid];
        for (int k = 0; k < 128; ++k) s += z1[k] * d2_w[tid * 128 + k];
        z2[tid] = lrelu_f(s);
    }
    __syncthreads();
    if (tid == 0) {
        float s = d3_b[0];
        for (int k = 0; k < 64; ++k) s += z2[k] * d3_w[k];
        out[b] = s;
    }
}

// ------------------------------------------------------------------
extern "C" void kernel_launch(void* const* d_in, const int* in_sizes, int n_in,
                              void* d_out, int out_size, void* d_ws, size_t ws_size,
                              hipStream_t stream) {
    const float* x     = (const float*)d_in[0];
    const float* w1a   = (const float*)d_in[1];
    const float* b1a   = (const float*)d_in[2];
    const float* w1b   = (const float*)d_in[3];
    const float* b1b   = (const float*)d_in[4];
    const float* w2a   = (const float*)d_in[5];
    const float* b2a   = (const float*)d_in[6];
    const float* w2b   = (const float*)d_in[7];
    const float* b2b   = (const float*)d_in[8];
    const float* e2nw  = (const float*)d_in[9];

    float* ws        = (float*)d_ws;
    float* A1        = ws;                     // 262144
    float* B1        = ws + 262144;            // 262144
    float* A2        = ws + 524288;            // 524288
    float* B2        = ws + 1048576;           // 524288
    float* nodes_raw = ws + 1572864;           // 16384
    float* rdegw     = ws + 1589248;           // 8192 (oversized, 2048 used)
    unsigned long long* adjw = (unsigned long long*)(ws + 1597440); // 8192 ull = 16384 f
    float* part      = ws + 1613824;           // 8388608
    unsigned short* w2aM  = (unsigned short*)(ws + 10002432);            // 8388608 shorts
    unsigned short* w2bM  = w2aM + 8388608;
    unsigned short* e2nwM = w2bM + 8388608;                              // 524288 shorts

    k_convert<<<dim3(512, 3), 256, 0, stream>>>(
        w2a, w2aM, 8388608 / 4,
        w2b, w2bM, 8388608 / 4,
        e2nw, e2nwM, 524288 / 4);
    hipMemsetAsync(nodes_raw, 0, 16384 * sizeof(float), stream);
    k_l1<<<dim3(256, 8, 2), 128, 0, stream>>>(x, w1a, b1a, w1b, b1b, A1, B1);
    k_adj<<<dim3(8, 8), 256, 0, stream>>>(x, adjw, rdegw);
    k_e2e<<<dim3(2, 8, 16), 512, 0, stream>>>(A1, B1, w2aM, w2bM, part);
    k_red<<<dim3(64, 16), 256, 0, stream>>>(part, b2a, b2b, A2, B2);
    k_e2n<<<dim3(16, 8, 8), 256, 0, stream>>>(A2, B2, e2nwM, nodes_raw);
    k_tail<<<dim3(8), 256, 0, stream>>>(adjw, rdegw, nodes_raw, (const float*)d_in[10],
        (const float*)d_in[11], (const float*)d_in[12], (const float*)d_in[13], (const float*)d_in[14],
        (const float*)d_in[15], (const float*)d_in[16], (const float*)d_in[17], (const float*)d_in[18],
        (const float*)d_in[19], (const float*)d_in[20], (const float*)d_in[21], (const float*)d_in[22],
        (const float*)d_in[23], (const float*)d_in[24], (const float*)d_in[25], (const float*)d_in[26],
        (float*)d_out);
}